// Round 7
// baseline (378.359 us; speedup 1.0000x reference)
//
#include <hip/hip_runtime.h>
#include <stdint.h>

// CycleFC 1w1a: out[b,o,h,w] = sum_c sign(x)[b,c,h,w+off(c)] * sign(W)[o,c] + bias[o]
// off(c) = (c+3)%7 - 3, zero-pad OOB. B=64, C=O=384, H=W=32.
//
// Binary-GEMM: pack signs (bit=1 iff <0) into 6 u64 words; out = bias2 - 2*popc(G^WB).
// bias2w[o][w] = bias[o] + Nvalid(w) + 2*popc(WB & ~V(w)) precomputed in prep.
//
// R12: achieved BW across R5-R11 tracks OUTSTANDING-REQUEST COUNT, not access
// pattern: 4-6 waves/SIMD w/ ~8 reqs in flight -> 2.1 TB/s; R10's 8x duplicated
// reads -> 3.4; write-only fills at max queue depth -> 6.7. All structures at
// ~24 waves/CU were equal (70-75us) because both phases are request-starved.
// Fix: pack = 2 rows/wave, BOTH 8xfloat4 batches issued before first use
// (16 outstanding/wave), 30 waves/CU. gemm = 2 px/lane (VGPR<=64), 256-thr
// blocks at 8 blocks/CU = 8 waves/SIMD, grid 2048. Math identical to R11.

#define IN_CH 384
#define HH 32
#define WW 32
#define BB 64

constexpr uint64_t P7(int t) {
  uint64_t m = 0;
  for (int k = 0; k < 64; ++k)
    if (k % 7 == t) m |= (1ull << k);
  return m;
}
__device__ __constant__ uint64_t Pm[7] = {P7(0), P7(1), P7(2), P7(3), P7(4), P7(5), P7(6)};

// ---------------- prep: one block (1 wave) per output channel o --------------
__global__ __launch_bounds__(64) void cyc_prep(const float* __restrict__ wgt,
                                               const float* __restrict__ bias,
                                               uint64_t* __restrict__ wbg,
                                               float* __restrict__ bias2w) {
  const int o = blockIdx.x;
  const int lane = threadIdx.x;
  __shared__ uint64_t wb_sh[6];
#pragma unroll
  for (int j = 0; j < 6; ++j) {
    uint64_t m = __ballot(wgt[o * IN_CH + j * 64 + lane] < 0.0f);
    if (lane == 0) wb_sh[j] = m;
  }
  __syncthreads();
  if (lane < 6) wbg[o * 6 + lane] = wb_sh[lane];
  if (lane < WW) {
    const int w = lane;
    int nv = 0, corr = 0;
#pragma unroll
    for (int j = 0; j < 6; ++j) {
      uint64_t V = 0;
#pragma unroll
      for (int d = -3; d <= 3; ++d) {
        int wd = w + d;
        if (wd >= 0 && wd < WW) V |= Pm[(d - j + 14) % 7];
      }
      nv += __popcll(V);
      corr += __popcll(wb_sh[j] & ~V);
    }
    bias2w[o * WW + w] = bias[o] + (float)nv + 2.0f * (float)corr;
  }
}

__device__ __forceinline__ uint32_t pack_row(const float4* __restrict__ xp,
                                             float4 (&v)[8]) {
  uint32_t myw = 0;
#pragma unroll
  for (int i = 0; i < 8; ++i) {
    myw |= (v[i].x < 0.0f ? 1u : 0u) << (i * 4 + 0);
    myw |= (v[i].y < 0.0f ? 1u : 0u) << (i * 4 + 1);
    myw |= (v[i].z < 0.0f ? 1u : 0u) << (i * 4 + 2);
    myw |= (v[i].w < 0.0f ? 1u : 0u) << (i * 4 + 3);
  }
  return myw;
}

__device__ __forceinline__ uint32_t bfly32(uint32_t s, int lane) {
  // 5-step 32x32 bit transpose across each 32-lane half (verified R7-R11).
  constexpr uint32_t Mt[5] = {0xFFFF0000u, 0xFF00FF00u, 0xF0F0F0F0u,
                              0xCCCCCCCCu, 0xAAAAAAAAu};
#pragma unroll
  for (int stp = 0; stp < 5; ++stp) {
    const int js = 16 >> stp;
    const uint32_t M = Mt[stp];
    uint32_t y = __shfl_xor(s, js);
    s = (lane & js) ? ((s & M) | ((y >> js) & ~M))
                    : ((s & ~M) | ((y << js) & M));
  }
  return s;
}

// ---------------- pack: x -> G, 2 rows/wave, 16 outstanding loads ------------
// block = (b, hq), 384 thr = 6 waves (wave = ch-group j). Rows hq and hq+16.
// grid = 64*16 = 1024; 5 blocks/CU = 30 waves/CU.
__global__ __launch_bounds__(384, 6) void cyc_pack(const float* __restrict__ x,
                                                   uint32_t* __restrict__ G32) {
  const int t = threadIdx.x;
  const int lane = t & 63, j = t >> 6;
  const int b = blockIdx.x >> 4;
  const int h = blockIdx.x & 15;  // rows h and h+16
  const int wcol = lane & 31, hhalf = lane >> 5;

  const int c = j * 64 + lane;
  const int off = ((c % 7 + 3) % 7) - 3;  // in [-3,3]
  const uint32_t shr = (off > 0) ? (uint32_t)off : 0u;
  const uint32_t shl = (off < 0) ? (uint32_t)(-off) : 0u;

  const float* xc = x + (size_t)(b * IN_CH + c) * (HH * WW);
  const float4* xpa = reinterpret_cast<const float4*>(xc + h * WW);
  const float4* xpb = reinterpret_cast<const float4*>(xc + (h + 16) * WW);

  // issue BOTH batches before any dependent use -> 16 loads in flight
  float4 va[8], vb[8];
#pragma unroll
  for (int i = 0; i < 8; ++i) va[i] = xpa[i];
#pragma unroll
  for (int i = 0; i < 8; ++i) vb[i] = xpb[i];

  uint32_t sa = pack_row(xpa, va);
  uint32_t sb = pack_row(xpb, vb);
  // pre-transpose cycle shift: bit w := bit (w+off); zero-fill == OOB pad
  sa = (sa >> shr) << shl;
  sb = (sb >> shr) << shl;
  sa = bfly32(sa, lane);
  sb = bfly32(sb, lane);

  // u32 half hhalf of u64 G[b][j][pixel]; 64 lanes = 256B contiguous store
  uint32_t* gout = G32 + ((size_t)b * 6 + j) * 2048;
  gout[((h)*32 + wcol) * 2 + hhalf] = sa;
  gout[((h + 16) * 32 + wcol) * 2 + hhalf] = sb;
}

// ---------------- gemm: G -> out, 8 waves/SIMD -------------------------------
// block = (b, oc24, pix-half), 256 thr = 4 waves, grid = 64*16*2 = 2048.
// Wave owns 6 o (36 weight u64 -> SGPR once); lane owns 2 px -> float2 stores.
__global__ __launch_bounds__(256, 8) void cyc_gemm(const uint64_t* __restrict__ G,
                                                   const uint64_t* __restrict__ wbg,
                                                   const float* __restrict__ bias2w,
                                                   float* __restrict__ out) {
  const int t = threadIdx.x;
  const int lane = t & 63, wave = t >> 6;
  const int bid = blockIdx.x;
  const int ph = bid & 1;
  const int oc = (bid >> 1) & 15;
  const int b = bid >> 5;
  const int o0 = oc * 24 + __builtin_amdgcn_readfirstlane(wave) * 6;

  // 36 weight u64, wave-uniform -> scalar loads, hoisted.
  uint64_t Wg[6][6];
  {
    const uint64_t* wp = wbg + (size_t)o0 * 6;
#pragma unroll
    for (int oo = 0; oo < 6; ++oo)
#pragma unroll
      for (int j = 0; j < 6; ++j) Wg[oo][j] = wp[oo * 6 + j];
  }
  // lane's 2 px have w = (2*lane)&31, +1 (pass-invariant mod 32)
  const int w2 = (2 * lane) & 31;
  float2 bs[6];
#pragma unroll
  for (int oo = 0; oo < 6; ++oo)
    bs[oo] = *reinterpret_cast<const float2*>(bias2w + (o0 + oo) * WW + w2);

  const uint64_t* gb = G + (size_t)b * 6 * 1024;
  float* ob = out + ((size_t)b * IN_CH + o0) * (HH * WW);

#pragma unroll
  for (int pass = 0; pass < 4; ++pass) {
    const int p0 = ph * 512 + pass * 128 + 2 * lane;
    // 6 ulonglong2 loads (2 px x 6 planes), all issued before use
    uint64_t ga[6], gc[6];
#pragma unroll
    for (int j = 0; j < 6; ++j) {
      const ulonglong2 u =
          *reinterpret_cast<const ulonglong2*>(gb + (size_t)j * 1024 + p0);
      ga[j] = u.x;
      gc[j] = u.y;
    }
#pragma unroll
    for (int oo = 0; oo < 6; ++oo) {
      int m0 = 0, m1 = 0;
#pragma unroll
      for (int j = 0; j < 6; ++j) {
        m0 += __popcll(ga[j] ^ Wg[oo][j]);
        m1 += __popcll(gc[j] ^ Wg[oo][j]);
      }
      float2 r;
      r.x = bs[oo].x - 2.0f * (float)m0;
      r.y = bs[oo].y - 2.0f * (float)m1;
      // 64 lanes x 8B consecutive -> 512B contiguous store
      *reinterpret_cast<float2*>(ob + (size_t)oo * (HH * WW) + p0) = r;
    }
  }
}

extern "C" void kernel_launch(void* const* d_in, const int* in_sizes, int n_in,
                              void* d_out, int out_size, void* d_ws, size_t ws_size,
                              hipStream_t stream) {
  const float* x = (const float*)d_in[0];
  const float* wgt = (const float*)d_in[1];
  const float* bias = (const float*)d_in[2];
  float* out = (float*)d_out;

  // ws layout: wbg @ 0 (18432 B), bias2w @ 18432 (49152 B), G @ 67584 (3 MB)
  uint64_t* wbg = (uint64_t*)d_ws;
  float* bias2w = (float*)((char*)d_ws + 18432);
  uint64_t* G = (uint64_t*)((char*)d_ws + 67584);

  cyc_prep<<<IN_CH, 64, 0, stream>>>(wgt, bias, wbg, bias2w);
  cyc_pack<<<BB * 16, 384, 0, stream>>>(x, (uint32_t*)G);
  cyc_gemm<<<BB * 16 * 2, 256, 0, stream>>>(G, wbg, bias2w, out);
}

// Round 9
// 197.048 us; speedup vs baseline: 1.9201x; 1.9201x over previous
//
#include <hip/hip_runtime.h>
#include <stdint.h>

// CycleFC 1w1a: out[b,o,h,w] = sum_c sign(x)[b,c,h,w+off(c)] * sign(W)[o,c] + bias[o]
// off(c) = (c+3)%7 - 3, zero-pad OOB. B=64, C=O=384, H=W=32.
//
// Binary-GEMM: pack signs (bit=1 iff <0) into 6 u64 words; out = bias2 - 2*popc(G^WB).
// bias2w[o][w] = bias[o] + Nvalid(w) + 2*popc(WB & ~V(w)) precomputed in prep.
//
// R14 == R13 resubmit (R13 hit an infra failure, never ran).
// R13: R12's launch_bounds(256,8) capped VGPR at 32 -> scratch spill (WRITE
// 98->417MB, FETCH 24->362MB = spill traffic, 210us). Fix: keep the occupancy
// push but remove register pressure BY CONSTRUCTION:
//  gemm: weights in LDS (24o x 6 u64 = 1.2KB/block, wave-uniform broadcast
//        ds_read, zero reg cost). 2 px/lane -> ~44 VGPR, no min-waves hint,
//        natural 8 waves/SIMD, grid 2048 = 8 blocks/CU. 512B/wave stores.
//  pack: 1 row-task/wave (8 float4 in flight), 256-thr blocks, grid 3072,
//        ~44 VGPR -> ~8 waves/SIMD. Shift+butterfly math verified R7-R12.

#define IN_CH 384
#define HH 32
#define WW 32
#define BB 64

constexpr uint64_t P7(int t) {
  uint64_t m = 0;
  for (int k = 0; k < 64; ++k)
    if (k % 7 == t) m |= (1ull << k);
  return m;
}
__device__ __constant__ uint64_t Pm[7] = {P7(0), P7(1), P7(2), P7(3), P7(4), P7(5), P7(6)};

// ---------------- prep: one block (1 wave) per output channel o --------------
__global__ __launch_bounds__(64) void cyc_prep(const float* __restrict__ wgt,
                                               const float* __restrict__ bias,
                                               uint64_t* __restrict__ wbg,
                                               float* __restrict__ bias2w) {
  const int o = blockIdx.x;
  const int lane = threadIdx.x;
  __shared__ uint64_t wb_sh[6];
#pragma unroll
  for (int j = 0; j < 6; ++j) {
    uint64_t m = __ballot(wgt[o * IN_CH + j * 64 + lane] < 0.0f);
    if (lane == 0) wb_sh[j] = m;
  }
  __syncthreads();
  if (lane < 6) wbg[o * 6 + lane] = wb_sh[lane];
  if (lane < WW) {
    const int w = lane;
    int nv = 0, corr = 0;
#pragma unroll
    for (int j = 0; j < 6; ++j) {
      uint64_t V = 0;
#pragma unroll
      for (int d = -3; d <= 3; ++d) {
        int wd = w + d;
        if (wd >= 0 && wd < WW) V |= Pm[(d - j + 14) % 7];
      }
      nv += __popcll(V);
      corr += __popcll(wb_sh[j] & ~V);
    }
    bias2w[o * WW + w] = bias[o] + (float)nv + 2.0f * (float)corr;
  }
}

__device__ __forceinline__ uint32_t bfly32(uint32_t s, int lane) {
  // 5-step 32x32 bit transpose across each 32-lane half (verified R7-R12).
  constexpr uint32_t Mt[5] = {0xFFFF0000u, 0xFF00FF00u, 0xF0F0F0F0u,
                              0xCCCCCCCCu, 0xAAAAAAAAu};
#pragma unroll
  for (int stp = 0; stp < 5; ++stp) {
    const int js = 16 >> stp;
    const uint32_t M = Mt[stp];
    uint32_t y = __shfl_xor(s, js);
    s = (lane & js) ? ((s & M) | ((y >> js) & ~M))
                    : ((s & ~M) | ((y << js) & M));
  }
  return s;
}

// ---------------- pack: x -> G, 1 row-task per wave --------------------------
// 256 thr = 4 waves; wave-task tau = bid*4+wave in [0, 64*32*6). grid = 3072.
// ~44 VGPR -> 8 waves/SIMD; 8 float4 loads in flight per wave.
__global__ __launch_bounds__(256) void cyc_pack(const float* __restrict__ x,
                                                uint32_t* __restrict__ G32) {
  const int t = threadIdx.x;
  const int lane = t & 63, wave = t >> 6;
  const int tau = blockIdx.x * 4 + wave;  // (b, h, j)
  const int b = tau / 192;
  const int rem = tau - b * 192;
  const int h = rem / 6;
  const int j = rem - h * 6;

  const int c = j * 64 + lane;
  const int off = ((c % 7 + 3) % 7) - 3;  // in [-3,3]
  const uint32_t shr = (off > 0) ? (uint32_t)off : 0u;
  const uint32_t shl = (off < 0) ? (uint32_t)(-off) : 0u;

  const float4* xp = reinterpret_cast<const float4*>(
      x + (size_t)((b * IN_CH + c) * HH + h) * WW);
  float4 v[8];
#pragma unroll
  for (int i = 0; i < 8; ++i) v[i] = xp[i];

  uint32_t myw = 0;
#pragma unroll
  for (int i = 0; i < 8; ++i) {
    myw |= (v[i].x < 0.0f ? 1u : 0u) << (i * 4 + 0);
    myw |= (v[i].y < 0.0f ? 1u : 0u) << (i * 4 + 1);
    myw |= (v[i].z < 0.0f ? 1u : 0u) << (i * 4 + 2);
    myw |= (v[i].w < 0.0f ? 1u : 0u) << (i * 4 + 3);
  }
  // pre-transpose cycle shift: bit w := bit (w+off); zero-fill == OOB pad
  uint32_t s = (myw >> shr) << shl;  // one of shr/shl is 0
  s = bfly32(s, lane);
  // u32 half (lane>>5) of u64 G[b][j][pixel], pixel = h*32 + (lane&31).
  // Wave's 64 stores cover one contiguous 256B region.
  G32[(((size_t)b * 6 + j) * 1024 + h * 32 + (lane & 31)) * 2 + (lane >> 5)] = s;
}

// ---------------- gemm: G -> out, LDS weights, 8 waves/SIMD ------------------
// block = (b, px-half, 24-o chunk), 256 thr, grid = 64*2*16 = 2048.
// Weights in LDS (broadcast reads, zero reg cost); lane owns 2 consecutive px.
__global__ __launch_bounds__(256) void cyc_gemm(const uint64_t* __restrict__ G,
                                                const uint64_t* __restrict__ wbg,
                                                const float* __restrict__ bias2w,
                                                float* __restrict__ out) {
  __shared__ uint64_t sW[24 * 6];  // 1152 B
  const int t = threadIdx.x;
  const int bid = blockIdx.x;
  const int oc = bid & 15;
  const int ph = (bid >> 4) & 1;
  const int b = bid >> 5;
  const int o0 = oc * 24;

  if (t < 144) sW[t] = wbg[o0 * 6 + t];
  __syncthreads();

  const int px = ph * 512 + 2 * t;  // 2 consecutive pixels per thread
  const uint64_t* gb = G + (size_t)b * 6 * 1024 + px;
  uint64_t ga[6], gc[6];
#pragma unroll
  for (int j = 0; j < 6; ++j) {
    const ulonglong2 u = *reinterpret_cast<const ulonglong2*>(gb + (size_t)j * 1024);
    ga[j] = u.x;
    gc[j] = u.y;
  }
  const int w2 = px & 31;
  const float* bp = bias2w + o0 * WW + w2;
  float* ob = out + ((size_t)b * IN_CH + o0) * (HH * WW) + px;

#pragma unroll 4
  for (int oo = 0; oo < 24; ++oo) {
    const uint64_t w0 = sW[oo * 6 + 0], w1 = sW[oo * 6 + 1], w2u = sW[oo * 6 + 2];
    const uint64_t w3 = sW[oo * 6 + 3], w4 = sW[oo * 6 + 4], w5 = sW[oo * 6 + 5];
    int m0 = __popcll(ga[0] ^ w0) + __popcll(ga[1] ^ w1) + __popcll(ga[2] ^ w2u) +
             __popcll(ga[3] ^ w3) + __popcll(ga[4] ^ w4) + __popcll(ga[5] ^ w5);
    int m1 = __popcll(gc[0] ^ w0) + __popcll(gc[1] ^ w1) + __popcll(gc[2] ^ w2u) +
             __popcll(gc[3] ^ w3) + __popcll(gc[4] ^ w4) + __popcll(gc[5] ^ w5);
    const float2 bsv = *reinterpret_cast<const float2*>(bp + oo * WW);
    float2 r;
    r.x = bsv.x - 2.0f * (float)m0;
    r.y = bsv.y - 2.0f * (float)m1;
    // 256 thr x 8B consecutive -> 2KB contiguous store per o across the block
    *reinterpret_cast<float2*>(ob + oo * (HH * WW)) = r;
  }
}

extern "C" void kernel_launch(void* const* d_in, const int* in_sizes, int n_in,
                              void* d_out, int out_size, void* d_ws, size_t ws_size,
                              hipStream_t stream) {
  const float* x = (const float*)d_in[0];
  const float* wgt = (const float*)d_in[1];
  const float* bias = (const float*)d_in[2];
  float* out = (float*)d_out;

  // ws layout: wbg @ 0 (18432 B), bias2w @ 18432 (49152 B), G @ 67584 (3 MB)
  uint64_t* wbg = (uint64_t*)d_ws;
  float* bias2w = (float*)((char*)d_ws + 18432);
  uint64_t* G = (uint64_t*)((char*)d_ws + 67584);

  cyc_prep<<<IN_CH, 64, 0, stream>>>(wgt, bias, wbg, bias2w);
  cyc_pack<<<BB * 32 * 6 / 4, 256, 0, stream>>>(x, (uint32_t*)G);
  cyc_gemm<<<BB * 2 * 16, 256, 0, stream>>>(G, wbg, bias2w, out);
}